// Round 15
// baseline (912.452 us; speedup 1.0000x reference)
//
#include <hip/hip_runtime.h>
#include <math.h>

#define NTOK   16384
#define DDIM   1024
#define HDIM   128
#define NEXP   32
#define NROUTE 30
#define TOPK   4
#define TS     64
#define NJOBS_F 1696        // 8*212 job slots (worst case 1144 routed + 256 pair)
#define CPX_F   212
#define SLAB   ((size_t)NTOK * DDIM)
#define NB_ROUTER 512
#define NB_FUSED  (NB_ROUTER + 4608)

typedef short bf16x8 __attribute__((ext_vector_type(8)));
typedef float f32x16 __attribute__((ext_vector_type(16)));
typedef unsigned int u32x4 __attribute__((ext_vector_type(4)));
typedef unsigned short u16;

__device__ __forceinline__ float sigmoidf_(float x) { return 1.f / (1.f + expf(-x)); }

__device__ __forceinline__ u16 f2bf(float x) {
  unsigned u = __float_as_uint(x);
  u += 0x7fffu + ((u >> 16) & 1u);
  return (u16)(u >> 16);
}
__device__ __forceinline__ float bf2f(u16 v) {
  return __uint_as_float(((unsigned)v) << 16);
}

__device__ __forceinline__ f32x16 mfma32(uint4 a, uint4 b, f32x16 c) {
  union { uint4 u; bf16x8 h; } A, B;
  A.u = a; B.u = b;
  return __builtin_amdgcn_mfma_f32_32x32x16_bf16(A.h, B.h, c, 0, 0, 0);
}

__device__ __forceinline__ void gload16(const void* g, void* l) {
  __builtin_amdgcn_global_load_lds(
      (const __attribute__((address_space(1))) unsigned int*)g,
      (__attribute__((address_space(3))) unsigned int*)l, 16, 0, 0);
}

// lgkm-only barrier: LDS writes visible; vmem prefetch stays in flight.
__device__ __forceinline__ void lgkm_bar() {
  asm volatile("s_waitcnt lgkmcnt(0)\ns_barrier" ::: "memory");
}

// ---------------- fused router + prep, one launch ----------------
// bid < 512: router block (32 tokens; lane owns k in {s*256+lane*4+j} ->
//            every SI/ES float4 load is fully coalesced, 16B lane stride).
// bid >= 512: prep block (cvt X / pack K / pack V).
// Kf[e][kc][s][wn][lane][8]: element K[e][kc*128+(s*2+khalf)*8+j][wn*32+l31]
// Vf[e][dc][s][wn][lane][8]: element V[e][(s*2+khalf)*8+j][dc*128+wn*32+l31]
__global__ __launch_bounds__(256, 2) void prep_router_kernel(
    const float* __restrict__ X, u16* __restrict__ Xb,
    const float* __restrict__ K, u16* __restrict__ Kf,
    const float* __restrict__ V, u16* __restrict__ Vf,
    const float* __restrict__ SI, const float* __restrict__ ES,
    const float* __restrict__ bias, float* __restrict__ out_sel,
    float* __restrict__ w6, int* __restrict__ sel_e, int* __restrict__ counts)
{
  __shared__ __align__(16) char lds[66048];   // prep: t[128][129]; router: pbuf+aff+hist
  const int tid = threadIdx.x;

  if (blockIdx.x < NB_ROUTER) {
    // ================= router block =================
    const int wave = tid >> 6, lane = tid & 63;
    const int tok0 = blockIdx.x * 32 + wave * 8;
    float (*pbuf)[65] = ((float (*)[65])lds) + wave * 32;   // wave-private 32x65
    float (*aff)[33]  = (float (*)[33])(lds + 33280);       // [32 tok][33]
    int* hist = (int*)(lds + 37504);                        // [4][32]

    if (tid < 128) hist[tid] = 0;

    // coalesced token fragments: k = s*256 + lane*4 + j
    float x[8][16];
#pragma unroll
    for (int t = 0; t < 8; ++t) {
      const float* xp = SI + (size_t)(tok0 + t) * DDIM + lane * 4;
#pragma unroll
      for (int s = 0; s < 4; ++s) {
        const float4 v = *(const float4*)(xp + s * 256);
        x[t][s*4+0]=v.x; x[t][s*4+1]=v.y; x[t][s*4+2]=v.z; x[t][s*4+3]=v.w;
      }
    }

#pragma unroll
    for (int g = 0; g < 8; ++g) {               // 4 experts per group
#pragma unroll
      for (int ei = 0; ei < 4; ++ei) {
        const int e = g * 4 + ei;
        float es[16];
        const float* ep = ES + (size_t)e * DDIM + lane * 4;
#pragma unroll
        for (int s = 0; s < 4; ++s) {
          const float4 v = *(const float4*)(ep + s * 256);
          es[s*4+0]=v.x; es[s*4+1]=v.y; es[s*4+2]=v.z; es[s*4+3]=v.w;
        }
#pragma unroll
        for (int t = 0; t < 8; ++t) {
          float p = 0.f;
#pragma unroll
          for (int u = 0; u < 16; ++u) p = fmaf(x[t][u], es[u], p);
          pbuf[ei * 8 + t][lane] = p;
        }
      }
      // intra-wave transpose reduce (stride-65 rows: conflict-free)
      const int pr = lane & 31, hf = lane >> 5;
      const float* src = &pbuf[pr][hf * 32];
      float4 s4 = make_float4(0.f, 0.f, 0.f, 0.f);
#pragma unroll
      for (int j = 0; j < 8; ++j) {
        const float4 v = *(const float4*)(src + j * 4);
        s4.x += v.x; s4.y += v.y; s4.z += v.z; s4.w += v.w;
      }
      float s = (s4.x + s4.y) + (s4.z + s4.w);
      s += __shfl_xor(s, 32, 64);
      if (hf == 0) aff[wave * 8 + (pr & 7)][g * 4 + (pr >> 3)] = s;
    }
    __syncthreads();               // hist zeroed + all aff visible

    if (lane < 8) {
      const int tok = tok0 + lane;
      float af[NEXP];
#pragma unroll
      for (int e2 = 0; e2 < NEXP; ++e2)
        af[e2] = sigmoidf_(aff[wave * 8 + lane][e2]);
      float sc[NROUTE];
#pragma unroll
      for (int e2 = 0; e2 < NROUTE; ++e2) sc[e2] = af[e2] + bias[e2];
      unsigned used = 0u;
      int idx[6];
#pragma unroll
      for (int j = 0; j < TOPK; ++j) {
        float bv = -1e30f; int best = 0;
#pragma unroll
        for (int e2 = 0; e2 < NROUTE; ++e2)
          if (!((used >> e2) & 1u) && sc[e2] > bv) { bv = sc[e2]; best = e2; }
        used |= (1u << best);
        idx[j] = best;
      }
      idx[4] = 30; idx[5] = 31;
#pragma unroll
      for (int j = 0; j < 6; ++j) {
        out_sel[(size_t)tok * 6 + j] = (float)idx[j];
        w6[(size_t)tok * 6 + j] = af[idx[j]];
      }
#pragma unroll
      for (int j = 0; j < TOPK; ++j) {
        sel_e[(size_t)tok * TOPK + j] = idx[j];
        atomicAdd(&hist[j * NEXP + idx[j]], 1);
      }
    }
    __syncthreads();
    if (tid < 128) {
      const int c = hist[tid];
      if (c) atomicAdd(&counts[tid], c);
    }
    return;
  }

  // ================= prep block =================
  int b = blockIdx.x - NB_ROUTER;               // [0,4608)
  float (*t)[129] = (float (*)[129])lds;

  if (b < 4096) {               // ---- cvt X ----
    const size_t base = ((size_t)b * 256 + tid) * 16;
    u16 v[16];
#pragma unroll
    for (int i = 0; i < 4; ++i) {
      const float4 f = *(const float4*)(X + base + i * 4);
      v[i*4+0] = f2bf(f.x); v[i*4+1] = f2bf(f.y);
      v[i*4+2] = f2bf(f.z); v[i*4+3] = f2bf(f.w);
    }
    *(uint4*)(Xb + base) = *(const uint4*)v;
    *(uint4*)(Xb + base + 8) = *(const uint4*)(v + 8);
    return;
  }
  b -= 4096;
  if (b < 256) {                // ---- prep K ----
    const int kc = b & 7, e = b >> 3;
#pragma unroll
    for (int i = 0; i < 64; ++i) {
      const int g = tid + i * 256;
      const int d = g >> 7, h = g & 127;
      t[d][h] = K[((size_t)e * DDIM + kc * 128 + d) * HDIM + h];
    }
    __syncthreads();
    u16* dst = Kf + ((size_t)e * 8 + kc) * 16384;
#pragma unroll
    for (int i = 0; i < 64; ++i) {
      const int f = tid + i * 256;
      const int s = f >> 11, wn = (f >> 9) & 3, l = (f >> 3) & 63, j = f & 7;
      const int khalf = l >> 5, l31 = l & 31;
      dst[f] = f2bf(t[(s * 2 + khalf) * 8 + j][wn * 32 + l31]);
    }
    return;
  }
  b -= 256;                     // ---- prep V ----
  {
    const int dc = b & 7, e = b >> 3;
#pragma unroll
    for (int i = 0; i < 64; ++i) {
      const int g = tid + i * 256;
      const int h = g >> 7, dl = g & 127;
      t[h][dl] = V[((size_t)e * HDIM + h) * DDIM + dc * 128 + dl];
    }
    __syncthreads();
    u16* dst = Vf + ((size_t)e * 8 + dc) * 16384;
#pragma unroll
    for (int i = 0; i < 64; ++i) {
      const int f = tid + i * 256;
      const int s = f >> 11, wn = (f >> 9) & 3, l = (f >> 3) & 63, j = f & 7;
      const int khalf = l >> 5, l31 = l & 31;
      dst[f] = f2bf(t[(s * 2 + khalf) * 8 + j][wn * 32 + l31]);
    }
  }
}

// ---------------- scan: offsets + fused job map (routed + 256 shared-pair) ----------------
__global__ __launch_bounds__(256) void scan_kernel(const int* __restrict__ counts,
                                                   int* __restrict__ offsets,
                                                   int4* __restrict__ jm)
{
  __shared__ int c4[30][4];
  __shared__ int off4[30][4];
  __shared__ int nch[32];
  __shared__ int joff[31];
  const int tid = threadIdx.x;

  if (tid < 4) {
    int off = 0;
    for (int e = 0; e < NROUTE; ++e) {
      const int c = counts[tid * NEXP + e];
      offsets[tid * NEXP + e] = off;
      c4[e][tid] = c; off4[e][tid] = off;
      off += c;
    }
  }
  __syncthreads();
  if (tid < NROUTE) {
    int n = 0;
#pragma unroll
    for (int r = 0; r < 4; ++r) n += (c4[tid][r] + TS - 1) / TS;
    nch[tid] = n;
  }
  __syncthreads();
  if (tid == 0) {
    int run = 0;
    for (int e = 0; e < NROUTE; ++e) { joff[e] = run; run += nch[e]; }
    joff[NROUTE] = run;
  }
  __syncthreads();
  const int rt = joff[NROUTE];

  if (tid < NROUTE) {
    const int e = tid;
    int idx = joff[e];
    for (int r = 0; r < 4; ++r) {
      const int c = c4[e][r];
      for (int ch = 0; ch * TS < c; ++ch)
        jm[idx++] = make_int4(e, off4[e][r] + ch * TS, min(TS, c - ch * TS), r);
    }
  }
  // shared experts: 256 PAIR jobs (e30 then e31 in one block), rank tag 4
  jm[rt + tid] = make_int4(30, tid * TS, TS, 4);
  for (int i = rt + 256 + tid; i < NJOBS_F; i += 256)
    jm[i] = make_int4(0, 0, 0, 0);
}

// ---------------- scatter (routed ranks only) ----------------
__global__ __launch_bounds__(256) void scatter_kernel(
    const int* __restrict__ sel_e, const float* __restrict__ w6,
    const int* __restrict__ offsets, int* __restrict__ cursor,
    int* __restrict__ list_tok, float* __restrict__ list_w)
{
  const int t = blockIdx.x * 256 + threadIdx.x;
  if (t >= NTOK) return;
#pragma unroll
  for (int j = 0; j < TOPK; ++j) {
    const int e   = sel_e[(size_t)t * TOPK + j];
    const int pos = atomicAdd(&cursor[j * NEXP + e], 1);
    const int dst = j * NTOK + offsets[j * NEXP + e] + pos;
    list_tok[dst] = t;
    list_w[dst]   = w6[(size_t)t * 6 + j];
  }
}

// ---------------- fused MFMA FFN (pair jobs compute e30 then e31) ----------------
__device__ __forceinline__ void loadb(uint4* b, const u16* __restrict__ base,
                                      int c, int wid, int lane) {
#pragma unroll
  for (int s = 0; s < 8; ++s)
    b[s] = *(const uint4*)(base + (size_t)(((c * 8 + s) * 4 + wid) * 512) + lane * 8);
}

__global__ __launch_bounds__(256, 2) void ffn_kernel(
    const u16* __restrict__ Xb, const u16* __restrict__ Kf, const u16* __restrict__ Vf,
    const int4* __restrict__ jm, const int* __restrict__ list_tok,
    const float* __restrict__ list_w, const float* __restrict__ w6,
    u16* __restrict__ part)
{
  __shared__ __align__(16) u16 Xs[2][8192];    // 2 x 16KB X chunks
  __shared__ __align__(16) u16 Hs[TS * 128];   // 16KB
  __shared__ int   s_tok[TS];
  __shared__ float s_w[TS], s_w2[TS];

  const int bid = blockIdx.x;
  const int4 J = jm[(bid & 7) * CPX_F + (bid >> 3)];
  const int nrow = J.z;
  if (nrow == 0) return;
  const int e0 = J.x, base = J.y, rank = J.w;
  const bool sh2 = (rank == 4);
  const int tid = threadIdx.x;
  const int wid = tid >> 6, lane = tid & 63;
  const int l31 = lane & 31, khalf = lane >> 5;
  const int sx = l31 & 15;

  const int*   lt  = list_tok + rank * NTOK + base;
  const float* lww = list_w  + rank * NTOK + base;

  size_t srcoff[4];
#pragma unroll
  for (int u = 0; u < 4; ++u) {
    const int r  = wid * 16 + u * 4 + (lane >> 4);
    const int rr = (r < nrow) ? r : 0;
    const int tk = sh2 ? (base + rr) : lt[rr];
    srcoff[u] = (size_t)tk * DDIM + (size_t)(((lane & 15) ^ (r & 15)) << 3);
  }

  #define STAGE_A(kc_, buf_) do { \
    _Pragma("unroll") \
    for (int u_ = 0; u_ < 4; ++u_) \
      gload16(Xb + srcoff[u_] + (kc_) * 128, &Xs[buf_][(wid * 16 + u_ * 4) * 128]); \
  } while (0)

  uint4 bb[2][8];
  STAGE_A(0, 0);
  loadb(bb[0], Kf + (size_t)e0 * 131072, 0, wid, lane);

  if (tid < TS) {
    int t = 0; float w = 0.f, w2 = 0.f;
    if (sh2) { t = base + tid; w = w6[(size_t)t * 6 + 4]; w2 = w6[(size_t)t * 6 + 5]; }
    else if (tid < nrow) { t = lt[tid]; w = lww[tid]; }
    s_tok[tid] = t; s_w[tid] = w; s_w2[tid] = w2;
  }
  lgkm_bar();                    // s_tok visible; staged vmem NOT drained

  unsigned ob0[16], ob1[16]; bool ov0[16], ov1[16];
#pragma unroll
  for (int r = 0; r < 16; ++r) {
    const int row0 = (r & 3) + 8 * (r >> 2) + 4 * khalf;
    const int row1 = row0 + 32;
    ov0[r] = row0 < nrow; ov1[r] = row1 < nrow;
    ob0[r] = (unsigned)s_tok[row0] * DDIM;
    ob1[r] = (unsigned)s_tok[row1] * DDIM;
  }

  u16* pp = part + (size_t)(sh2 ? 4 : rank) * SLAB;
  const int nee = sh2 ? 2 : 1;

  for (int ee = 0; ee < nee; ++ee) {
    const u16* Kf_e = Kf + (size_t)(e0 + ee) * 131072;
    const u16* Vf_e = Vf + (size_t)(e0 + ee) * 131072;

    f32x16 acc0, acc1;
#pragma unroll
    for (int i = 0; i < 16; ++i) { acc0[i] = 0.f; acc1[i] = 0.f; }

    // ---- GEMM1: Hs[64][128] = X @ keys[e] ----
#pragma unroll
    for (int kc = 0; kc < 8; ++kc) {
      const int cur = kc & 1;
      asm volatile("s_barrier" ::: "memory");             // Xs[cur^1] readers done
      __builtin_amdgcn_sched_barrier(0);
      if (kc < 7) { STAGE_A(kc + 1, cur ^ 1); loadb(bb[cur ^ 1], Kf_e, kc + 1, wid, lane); }
      else        { loadb(bb[cur ^ 1], Vf_e, 0, wid, lane); }
      if (kc < 7) asm volatile("s_waitcnt vmcnt(12)" ::: "memory");  // own stage(kc) done
      else        asm volatile("s_waitcnt vmcnt(8)"  ::: "memory");
      asm volatile("s_barrier" ::: "memory");             // all waves' stage(kc) landed
      __builtin_amdgcn_sched_barrier(0);
#pragma unroll
      for (int s = 0; s < 8; ++s) {
        const int so = (((s * 2 + khalf) ^ sx) << 3);
        const uint4 a0 = *(const uint4*)(&Xs[cur][l31 * 128 + so]);
        const uint4 a1 = *(const uint4*)(&Xs[cur][(32 + l31) * 128 + so]);
        acc0 = mfma32(a0, bb[cur][s], acc0);
        acc1 = mfma32(a1, bb[cur][s], acc1);
      }
    }

    // silu * w -> Hs (bf16, XOR-swizzled rows)
    {
      const int hcol = wid * 32 + l31;
      const float* swp = ee ? s_w2 : s_w;
#pragma unroll
      for (int r = 0; r < 16; ++r) {
        const int row0 = (r & 3) + 8 * (r >> 2) + 4 * khalf;
        float v0 = acc0[r];
        v0 = v0 / (1.f + expf(-v0)) * swp[row0];
        Hs[row0 * 128 + ((((hcol >> 3) ^ (row0 & 15)) << 3) | (hcol & 7))] = f2bf(v0);
        const int row1 = row0 + 32;
        float v1 = acc1[r];
        v1 = v1 / (1.f + expf(-v1)) * swp[row1];
        Hs[row1 * 128 + ((((hcol >> 3) ^ (row1 & 15)) << 3) | (hcol & 7))] = f2bf(v1);
      }
    }
    lgkm_bar();                  // Hs visible; V chunk-0 prefetch still in flight

    uint4 a20[8], a21[8];
#pragma unroll
    for (int s = 0; s < 8; ++s) {
      a20[s] = *(const uint4*)(Hs + l31 * 128 + (((s * 2 + khalf) ^ sx) << 3));
      a21[s] = *(const uint4*)(Hs + (32 + l31) * 128 + (((s * 2 + khalf) ^ sx) << 3));
    }

    // ---- GEMM2: slab (+)= Hs @ values[e] ----
#pragma unroll
    for (int dc = 0; dc < 8; ++dc) {
      const int cur = dc & 1;
      if (dc < 7) loadb(bb[cur ^ 1], Vf_e, dc + 1, wid, lane);
      else if (sh2 && ee == 0) loadb(bb[cur ^ 1], Kf + (size_t)31 * 131072, 0, wid, lane);
      if (dc == 6 && sh2 && ee == 0) STAGE_A(0, 0);  // e31's X chunk 0 (Xs reads all done)
      f32x16 o0, o1;
#pragma unroll
      for (int i = 0; i < 16; ++i) { o0[i] = 0.f; o1[i] = 0.f; }
#pragma unroll
      for (int s = 0; s < 8; ++s) {
        o0 = mfma32(a20[s], bb[cur][s], o0);
        o1 = mfma32(a21[s], bb[cur][s], o1);
      }
      const int col = dc * 128 + wid * 32 + l31;
#pragma unroll
      for (int r = 0; r < 16; ++r) {
        if (ov0[r]) {
          const size_t p = (size_t)ob0[r] + col;
          if (sh2) {
            if (ee == 0) pp[p] = f2bf(o0[r]);                       // normal: L2-hot for RMW
            else __builtin_nontemporal_store(f2bf(bf2f(pp[p]) + o0[r]), &pp[p]);
          } else __builtin_nontemporal_store(f2bf(o0[r]), &pp[p]);
        }
        if (ov1[r]) {
          const size_t p = (size_t)ob1[r] + col;
          if (sh2) {
            if (ee == 0) pp[p] = f2bf(o1[r]);
            else __builtin_nontemporal_store(f2bf(bf2f(pp[p]) + o1[r]), &pp[p]);
          } else __builtin_nontemporal_store(f2bf(o1[r]), &pp[p]);
        }
      }
    }
  }
  #undef STAGE_A
}

// ---------------- reduce: out = sum of 5 bf16 partial slabs (nt loads) ----------------
__global__ __launch_bounds__(256) void reduce_kernel(const u16* __restrict__ part,
                                                     float* __restrict__ out)
{
  const size_t i8 = ((size_t)blockIdx.x * 256 + threadIdx.x) * 8;
  float s[8];
#pragma unroll
  for (int j = 0; j < 8; ++j) s[j] = 0.f;
#pragma unroll
  for (int r = 0; r < 5; ++r) {
    const u32x4 v = __builtin_nontemporal_load((const u32x4*)(part + r * SLAB + i8));
#pragma unroll
    for (int q = 0; q < 4; ++q) {
      s[q*2+0] += __uint_as_float((v[q] & 0xffffu) << 16);
      s[q*2+1] += __uint_as_float(v[q] & 0xffff0000u);
    }
  }
  float4 o0 = make_float4(s[0], s[1], s[2], s[3]);
  float4 o1 = make_float4(s[4], s[5], s[6], s[7]);
  *(float4*)(out + i8) = o0;
  *(float4*)(out + i8 + 4) = o1;
}

extern "C" void kernel_launch(void* const* d_in, const int* in_sizes, int n_in,
                              void* d_out, int out_size, void* d_ws, size_t ws_size,
                              hipStream_t stream)
{
  const float* X    = (const float*)d_in[0];
  const float* SI   = (const float*)d_in[1];
  const float* keys = (const float*)d_in[2];
  const float* vals = (const float*)d_in[3];
  const float* ES   = (const float*)d_in[4];
  const float* bias = (const float*)d_in[5];
  float* out = (float*)d_out;
  float* out_sel = out + SLAB;

  char* ws = (char*)d_ws;
  int*   counts   = (int*)(ws + 0);
  int*   cursor   = (int*)(ws + 512);
  int*   offsets  = (int*)(ws + 1024);
  int4*  jm       = (int4*)(ws + 2048);
  int*   list_tok = (int*)(ws + 57344);
  float* list_w   = (float*)(ws + 450560);
  float* w6       = (float*)(ws + 919552);
  int*   sel_e    = (int*)(ws + 1312768);
  u16*   Xb       = (u16*)(ws + 1576960);        // 32MB
  u16*   Kf       = (u16*)(ws + 35131392);       // 8MB
  u16*   Vf       = (u16*)(ws + 43520000);       // 8MB
  u16*   part     = (u16*)(ws + 51908608);       // 5 x 32MB slabs

  hipMemsetAsync(counts, 0, 1024, stream);

  prep_router_kernel<<<NB_FUSED, 256, 0, stream>>>(X, Xb, keys, Kf, vals, Vf,
                                                   SI, ES, bias, out_sel, w6,
                                                   sel_e, counts);
  scan_kernel<<<1, 256, 0, stream>>>(counts, offsets, jm);
  scatter_kernel<<<NTOK / 256, 256, 0, stream>>>(sel_e, w6, offsets, cursor, list_tok, list_w);
  ffn_kernel<<<NJOBS_F, 256, 0, stream>>>(Xb, Kf, Vf, jm, list_tok, list_w, w6, part);
  reduce_kernel<<<SLAB / (256 * 8), 256, 0, stream>>>(part, out);
}

// Round 16
// 333.957 us; speedup vs baseline: 2.7322x; 2.7322x over previous
//
#include <hip/hip_runtime.h>
#include <math.h>

#define NTOK   16384
#define DDIM   1024
#define HDIM   128
#define NEXP   32
#define NROUTE 30
#define TOPK   4
#define TS     64
#define NJOBS_F 1696        // 8*212 job slots (worst case 1144 routed + 512 shared)
#define CPX_F   212
#define SLAB   ((size_t)NTOK * DDIM)
#define NB_ROUTER 512
#define NB_FUSED  (NB_ROUTER + 4608)

typedef short bf16x8 __attribute__((ext_vector_type(8)));
typedef float f32x16 __attribute__((ext_vector_type(16)));
typedef unsigned int u32x4 __attribute__((ext_vector_type(4)));
typedef unsigned short u16;

__device__ __forceinline__ float sigmoidf_(float x) { return 1.f / (1.f + expf(-x)); }

__device__ __forceinline__ u16 f2bf(float x) {
  unsigned u = __float_as_uint(x);
  u += 0x7fffu + ((u >> 16) & 1u);
  return (u16)(u >> 16);
}
__device__ __forceinline__ float bf2f(u16 v) {
  return __uint_as_float(((unsigned)v) << 16);
}

__device__ __forceinline__ f32x16 mfma32(uint4 a, uint4 b, f32x16 c) {
  union { uint4 u; bf16x8 h; } A, B;
  A.u = a; B.u = b;
  return __builtin_amdgcn_mfma_f32_32x32x16_bf16(A.h, B.h, c, 0, 0, 0);
}

__device__ __forceinline__ void gload16(const void* g, void* l) {
  __builtin_amdgcn_global_load_lds(
      (const __attribute__((address_space(1))) unsigned int*)g,
      (__attribute__((address_space(3))) unsigned int*)l, 16, 0, 0);
}

// lgkm-only barrier: LDS writes visible; vmem prefetch stays in flight.
__device__ __forceinline__ void lgkm_bar() {
  asm volatile("s_waitcnt lgkmcnt(0)\ns_barrier" ::: "memory");
}

// ---------------- fused router + prep, one launch ----------------
// bid < 512: router block (32 tokens; lane owns k in {s*256+lane*4+j} ->
//            every SI/ES float4 load is fully coalesced, 16B lane stride).
// bid >= 512: prep block (cvt X / pack K / pack V).
// Kf[e][kc][s][wn][lane][8]: element K[e][kc*128+(s*2+khalf)*8+j][wn*32+l31]
// Vf[e][dc][s][wn][lane][8]: element V[e][(s*2+khalf)*8+j][dc*128+wn*32+l31]
__global__ __launch_bounds__(256, 2) void prep_router_kernel(
    const float* __restrict__ X, u16* __restrict__ Xb,
    const float* __restrict__ K, u16* __restrict__ Kf,
    const float* __restrict__ V, u16* __restrict__ Vf,
    const float* __restrict__ SI, const float* __restrict__ ES,
    const float* __restrict__ bias, float* __restrict__ out_sel,
    float* __restrict__ w6, int* __restrict__ sel_e, int* __restrict__ counts)
{
  __shared__ __align__(16) char lds[66048];   // prep: t[128][129]; router: pbuf+aff+hist
  const int tid = threadIdx.x;

  if (blockIdx.x < NB_ROUTER) {
    // ================= router block =================
    const int wave = tid >> 6, lane = tid & 63;
    const int tok0 = blockIdx.x * 32 + wave * 8;
    float (*pbuf)[65] = ((float (*)[65])lds) + wave * 32;   // wave-private 32x65
    float (*aff)[33]  = (float (*)[33])(lds + 33280);       // [32 tok][33]
    int* hist = (int*)(lds + 37504);                        // [4][32]

    if (tid < 128) hist[tid] = 0;

    // coalesced token fragments: k = s*256 + lane*4 + j
    float x[8][16];
#pragma unroll
    for (int t = 0; t < 8; ++t) {
      const float* xp = SI + (size_t)(tok0 + t) * DDIM + lane * 4;
#pragma unroll
      for (int s = 0; s < 4; ++s) {
        const float4 v = *(const float4*)(xp + s * 256);
        x[t][s*4+0]=v.x; x[t][s*4+1]=v.y; x[t][s*4+2]=v.z; x[t][s*4+3]=v.w;
      }
    }

#pragma unroll
    for (int g = 0; g < 8; ++g) {               // 4 experts per group
#pragma unroll
      for (int ei = 0; ei < 4; ++ei) {
        const int e = g * 4 + ei;
        float es[16];
        const float* ep = ES + (size_t)e * DDIM + lane * 4;
#pragma unroll
        for (int s = 0; s < 4; ++s) {
          const float4 v = *(const float4*)(ep + s * 256);
          es[s*4+0]=v.x; es[s*4+1]=v.y; es[s*4+2]=v.z; es[s*4+3]=v.w;
        }
#pragma unroll
        for (int t = 0; t < 8; ++t) {
          float p = 0.f;
#pragma unroll
          for (int u = 0; u < 16; ++u) p = fmaf(x[t][u], es[u], p);
          pbuf[ei * 8 + t][lane] = p;
        }
      }
      // intra-wave transpose reduce (stride-65 rows: conflict-free)
      const int pr = lane & 31, hf = lane >> 5;
      const float* src = &pbuf[pr][hf * 32];
      float4 s4 = make_float4(0.f, 0.f, 0.f, 0.f);
#pragma unroll
      for (int j = 0; j < 8; ++j) {
        const float4 v = *(const float4*)(src + j * 4);
        s4.x += v.x; s4.y += v.y; s4.z += v.z; s4.w += v.w;
      }
      float s = (s4.x + s4.y) + (s4.z + s4.w);
      s += __shfl_xor(s, 32, 64);
      if (hf == 0) aff[wave * 8 + (pr & 7)][g * 4 + (pr >> 3)] = s;
    }
    __syncthreads();               // hist zeroed + all aff visible

    if (lane < 8) {
      const int tok = tok0 + lane;
      float af[NEXP];
#pragma unroll
      for (int e2 = 0; e2 < NEXP; ++e2)
        af[e2] = sigmoidf_(aff[wave * 8 + lane][e2]);
      float sc[NROUTE];
#pragma unroll
      for (int e2 = 0; e2 < NROUTE; ++e2) sc[e2] = af[e2] + bias[e2];
      unsigned used = 0u;
      int idx[6];
#pragma unroll
      for (int j = 0; j < TOPK; ++j) {
        float bv = -1e30f; int best = 0;
#pragma unroll
        for (int e2 = 0; e2 < NROUTE; ++e2)
          if (!((used >> e2) & 1u) && sc[e2] > bv) { bv = sc[e2]; best = e2; }
        used |= (1u << best);
        idx[j] = best;
      }
      idx[4] = 30; idx[5] = 31;
#pragma unroll
      for (int j = 0; j < 6; ++j) {
        out_sel[(size_t)tok * 6 + j] = (float)idx[j];
        w6[(size_t)tok * 6 + j] = af[idx[j]];
      }
#pragma unroll
      for (int j = 0; j < TOPK; ++j) {
        sel_e[(size_t)tok * TOPK + j] = idx[j];
        atomicAdd(&hist[j * NEXP + idx[j]], 1);
      }
    }
    __syncthreads();
    if (tid < 128) {
      const int c = hist[tid];
      if (c) atomicAdd(&counts[tid], c);
    }
    return;
  }

  // ================= prep block =================
  int b = blockIdx.x - NB_ROUTER;               // [0,4608)
  float (*t)[129] = (float (*)[129])lds;

  if (b < 4096) {               // ---- cvt X ----
    const size_t base = ((size_t)b * 256 + tid) * 16;
    u16 v[16];
#pragma unroll
    for (int i = 0; i < 4; ++i) {
      const float4 f = *(const float4*)(X + base + i * 4);
      v[i*4+0] = f2bf(f.x); v[i*4+1] = f2bf(f.y);
      v[i*4+2] = f2bf(f.z); v[i*4+3] = f2bf(f.w);
    }
    *(uint4*)(Xb + base) = *(const uint4*)v;
    *(uint4*)(Xb + base + 8) = *(const uint4*)(v + 8);
    return;
  }
  b -= 4096;
  if (b < 256) {                // ---- prep K ----
    const int kc = b & 7, e = b >> 3;
#pragma unroll
    for (int i = 0; i < 64; ++i) {
      const int g = tid + i * 256;
      const int d = g >> 7, h = g & 127;
      t[d][h] = K[((size_t)e * DDIM + kc * 128 + d) * HDIM + h];
    }
    __syncthreads();
    u16* dst = Kf + ((size_t)e * 8 + kc) * 16384;
#pragma unroll
    for (int i = 0; i < 64; ++i) {
      const int f = tid + i * 256;
      const int s = f >> 11, wn = (f >> 9) & 3, l = (f >> 3) & 63, j = f & 7;
      const int khalf = l >> 5, l31 = l & 31;
      dst[f] = f2bf(t[(s * 2 + khalf) * 8 + j][wn * 32 + l31]);
    }
    return;
  }
  b -= 256;                     // ---- prep V ----
  {
    const int dc = b & 7, e = b >> 3;
#pragma unroll
    for (int i = 0; i < 64; ++i) {
      const int g = tid + i * 256;
      const int h = g >> 7, dl = g & 127;
      t[h][dl] = V[((size_t)e * HDIM + h) * DDIM + dc * 128 + dl];
    }
    __syncthreads();
    u16* dst = Vf + ((size_t)e * 8 + dc) * 16384;
#pragma unroll
    for (int i = 0; i < 64; ++i) {
      const int f = tid + i * 256;
      const int s = f >> 11, wn = (f >> 9) & 3, l = (f >> 3) & 63, j = f & 7;
      const int khalf = l >> 5, l31 = l & 31;
      dst[f] = f2bf(t[(s * 2 + khalf) * 8 + j][wn * 32 + l31]);
    }
  }
}

// ---------------- scan: offsets + fused job map (expert-major routed + shared) ----------------
__global__ __launch_bounds__(256) void scan_kernel(const int* __restrict__ counts,
                                                   int* __restrict__ offsets,
                                                   int4* __restrict__ jm)
{
  __shared__ int c4[30][4];
  __shared__ int off4[30][4];
  __shared__ int nch[32];
  __shared__ int joff[31];
  const int tid = threadIdx.x;

  if (tid < 4) {
    int off = 0;
    for (int e = 0; e < NROUTE; ++e) {
      const int c = counts[tid * NEXP + e];
      offsets[tid * NEXP + e] = off;
      c4[e][tid] = c; off4[e][tid] = off;
      off += c;
    }
  }
  __syncthreads();
  if (tid < NROUTE) {
    int n = 0;
#pragma unroll
    for (int r = 0; r < 4; ++r) n += (c4[tid][r] + TS - 1) / TS;
    nch[tid] = n;
  }
  __syncthreads();
  if (tid == 0) {
    int run = 0;
    for (int e = 0; e < NROUTE; ++e) { joff[e] = run; run += nch[e]; }
    joff[NROUTE] = run;
  }
  __syncthreads();
  const int rt = joff[NROUTE];

  if (tid < NROUTE) {
    const int e = tid;
    int idx = joff[e];
    for (int r = 0; r < 4; ++r) {
      const int c = c4[e][r];
      for (int ch = 0; ch * TS < c; ++ch)
        jm[idx++] = make_int4(e, off4[e][r] + ch * TS, min(TS, c - ch * TS), r);
    }
  }
  // shared experts: 256 jobs each, rank tags 4 and 5 (identity lists)
  for (int i = tid; i < 512; i += 256)
    jm[rt + i] = make_int4(30 + (i >> 8), (i & 255) * TS, TS, 4 + (i >> 8));
  for (int i = rt + 512 + tid; i < NJOBS_F; i += 256)
    jm[i] = make_int4(0, 0, 0, 0);
}

// ---------------- scatter (routed ranks + shared identity lists 4,5) ----------------
__global__ __launch_bounds__(256) void scatter_kernel(
    const int* __restrict__ sel_e, const float* __restrict__ w6,
    const int* __restrict__ offsets, int* __restrict__ cursor,
    int* __restrict__ list_tok, float* __restrict__ list_w)
{
  const int t = blockIdx.x * 256 + threadIdx.x;
  if (t >= NTOK) return;
#pragma unroll
  for (int j = 0; j < TOPK; ++j) {
    const int e   = sel_e[(size_t)t * TOPK + j];
    const int pos = atomicAdd(&cursor[j * NEXP + e], 1);
    const int dst = j * NTOK + offsets[j * NEXP + e] + pos;
    list_tok[dst] = t;
    list_w[dst]   = w6[(size_t)t * 6 + j];
  }
  list_tok[4 * NTOK + t] = t; list_w[4 * NTOK + t] = w6[(size_t)t * 6 + 4];
  list_tok[5 * NTOK + t] = t; list_w[5 * NTOK + t] = w6[(size_t)t * 6 + 5];
}

// ---------------- fused MFMA FFN ----------------
// A (X tile) staged into LDS via global_load_lds (pre-swizzled per-lane global
// source, linear LDS dest), double-buffered; B register-direct dbuf.
// T4 chunk loop: barrier(A) -> issue stage(k+1) -> counted vmcnt (drains own
// stage(k), leaves stage(k+1) in flight) -> barrier(B) -> compute(k).
__device__ __forceinline__ void loadb(uint4* b, const u16* __restrict__ base,
                                      int c, int wid, int lane) {
#pragma unroll
  for (int s = 0; s < 8; ++s)
    b[s] = *(const uint4*)(base + (size_t)(((c * 8 + s) * 4 + wid) * 512) + lane * 8);
}

__global__ __launch_bounds__(256, 2) void ffn_kernel(
    const u16* __restrict__ Xb, const u16* __restrict__ Kf, const u16* __restrict__ Vf,
    const int4* __restrict__ jm, const int* __restrict__ list_tok,
    const float* __restrict__ list_w, u16* __restrict__ part)
{
  __shared__ __align__(16) u16 Xs[2][8192];    // 2 x 16KB X chunks
  __shared__ __align__(16) u16 Hs[TS * 128];   // 16KB
  __shared__ int   s_tok[TS];
  __shared__ float s_w[TS];

  const int bid = blockIdx.x;
  const int4 J = jm[(bid & 7) * CPX_F + (bid >> 3)];
  const int nrow = J.z;
  if (nrow == 0) return;
  const int e = J.x, base = J.y, rank = J.w;
  const int tid = threadIdx.x;
  const int wid = tid >> 6, lane = tid & 63;
  const int l31 = lane & 31, khalf = lane >> 5;
  const int sx = l31 & 15;

  const u16* Kf_e = Kf + (size_t)e * 131072;
  const u16* Vf_e = Vf + (size_t)e * 131072;
  const int*   lt  = list_tok + rank * NTOK + base;
  const float* lww = list_w  + rank * NTOK + base;

  size_t srcoff[4];
#pragma unroll
  for (int u = 0; u < 4; ++u) {
    const int r  = wid * 16 + u * 4 + (lane >> 4);
    const int rr = (r < nrow) ? r : 0;
    srcoff[u] = (size_t)lt[rr] * DDIM + (size_t)(((lane & 15) ^ (r & 15)) << 3);
  }

  #define STAGE_A(kc_, buf_) do { \
    _Pragma("unroll") \
    for (int u_ = 0; u_ < 4; ++u_) \
      gload16(Xb + srcoff[u_] + (kc_) * 128, &Xs[buf_][(wid * 16 + u_ * 4) * 128]); \
  } while (0)

  uint4 bb[2][8];
  STAGE_A(0, 0);
  loadb(bb[0], Kf_e, 0, wid, lane);

  if (tid < TS) {
    int t = 0; float w = 0.f;
    if (tid < nrow) { t = lt[tid]; w = lww[tid]; }
    s_tok[tid] = t; s_w[tid] = w;
  }
  lgkm_bar();                    // s_tok visible; staged vmem NOT drained

  f32x16 acc0, acc1;
#pragma unroll
  for (int i = 0; i < 16; ++i) { acc0[i] = 0.f; acc1[i] = 0.f; }

  // ---- GEMM1: Hs[64][128] = X @ keys[e] ----
#pragma unroll
  for (int kc = 0; kc < 8; ++kc) {
    const int cur = kc & 1;
    asm volatile("s_barrier" ::: "memory");             // Xs[cur^1] readers done
    __builtin_amdgcn_sched_barrier(0);
    if (kc < 7) { STAGE_A(kc + 1, cur ^ 1); loadb(bb[cur ^ 1], Kf_e, kc + 1, wid, lane); }
    else        { loadb(bb[cur ^ 1], Vf_e, 0, wid, lane); }
    if (kc < 7) asm volatile("s_waitcnt vmcnt(12)" ::: "memory");  // own stage(kc) done
    else        asm volatile("s_waitcnt vmcnt(8)"  ::: "memory");
    asm volatile("s_barrier" ::: "memory");             // all waves' stage(kc) landed
    __builtin_amdgcn_sched_barrier(0);
#pragma unroll
    for (int s = 0; s < 8; ++s) {
      const int so = (((s * 2 + khalf) ^ sx) << 3);
      const uint4 a0 = *(const uint4*)(&Xs[cur][l31 * 128 + so]);
      const uint4 a1 = *(const uint4*)(&Xs[cur][(32 + l31) * 128 + so]);
      acc0 = mfma32(a0, bb[cur][s], acc0);
      acc1 = mfma32(a1, bb[cur][s], acc1);
    }
  }

  // silu * w -> Hs (bf16, XOR-swizzled rows)
  {
    const int hcol = wid * 32 + l31;
#pragma unroll
    for (int r = 0; r < 16; ++r) {
      const int row0 = (r & 3) + 8 * (r >> 2) + 4 * khalf;
      float v0 = acc0[r];
      v0 = v0 / (1.f + expf(-v0)) * s_w[row0];
      Hs[row0 * 128 + ((((hcol >> 3) ^ (row0 & 15)) << 3) | (hcol & 7))] = f2bf(v0);
      const int row1 = row0 + 32;
      float v1 = acc1[r];
      v1 = v1 / (1.f + expf(-v1)) * s_w[row1];
      Hs[row1 * 128 + ((((hcol >> 3) ^ (row1 & 15)) << 3) | (hcol & 7))] = f2bf(v1);
    }
  }
  lgkm_bar();                    // Hs visible; V chunk-0 prefetch still in flight

  uint4 a20[8], a21[8];
#pragma unroll
  for (int s = 0; s < 8; ++s) {
    a20[s] = *(const uint4*)(Hs + l31 * 128 + (((s * 2 + khalf) ^ sx) << 3));
    a21[s] = *(const uint4*)(Hs + (32 + l31) * 128 + (((s * 2 + khalf) ^ sx) << 3));
  }

  unsigned ob0[16], ob1[16]; bool ov0[16], ov1[16];
#pragma unroll
  for (int r = 0; r < 16; ++r) {
    const int row0 = (r & 3) + 8 * (r >> 2) + 4 * khalf;
    const int row1 = row0 + 32;
    ov0[r] = row0 < nrow; ov1[r] = row1 < nrow;
    ob0[r] = (unsigned)s_tok[row0] * DDIM;
    ob1[r] = (unsigned)s_tok[row1] * DDIM;
  }

  u16* pp = part + (size_t)rank * SLAB;

  // ---- GEMM2: part[rank] = Hs @ values[e] (non-temporal streaming stores) ----
#pragma unroll
  for (int dc = 0; dc < 8; ++dc) {
    const int cur = dc & 1;
    if (dc < 7) loadb(bb[cur ^ 1], Vf_e, dc + 1, wid, lane);
    f32x16 o0, o1;
#pragma unroll
    for (int i = 0; i < 16; ++i) { o0[i] = 0.f; o1[i] = 0.f; }
#pragma unroll
    for (int s = 0; s < 8; ++s) {
      o0 = mfma32(a20[s], bb[cur][s], o0);
      o1 = mfma32(a21[s], bb[cur][s], o1);
    }
    const int col = dc * 128 + wid * 32 + l31;
#pragma unroll
    for (int r = 0; r < 16; ++r) {
      if (ov0[r]) __builtin_nontemporal_store(f2bf(o0[r]), &pp[(size_t)ob0[r] + col]);
      if (ov1[r]) __builtin_nontemporal_store(f2bf(o1[r]), &pp[(size_t)ob1[r] + col]);
    }
  }
  #undef STAGE_A
}

// ---------------- reduce: out = sum of 6 bf16 partial slabs (nt loads/stores) ----------------
__global__ __launch_bounds__(256) void reduce_kernel(const u16* __restrict__ part,
                                                     float* __restrict__ out)
{
  const size_t i8 = ((size_t)blockIdx.x * 256 + threadIdx.x) * 8;
  float s[8];
#pragma unroll
  for (int j = 0; j < 8; ++j) s[j] = 0.f;
#pragma unroll
  for (int r = 0; r < 6; ++r) {
    const u32x4 v = __builtin_nontemporal_load((const u32x4*)(part + r * SLAB + i8));
#pragma unroll
    for (int q = 0; q < 4; ++q) {
      s[q*2+0] += __uint_as_float((v[q] & 0xffffu) << 16);
      s[q*2+1] += __uint_as_float(v[q] & 0xffff0000u);
    }
  }
#pragma unroll
  for (int j = 0; j < 8; ++j)
    __builtin_nontemporal_store(s[j], out + i8 + j);
}

extern "C" void kernel_launch(void* const* d_in, const int* in_sizes, int n_in,
                              void* d_out, int out_size, void* d_ws, size_t ws_size,
                              hipStream_t stream)
{
  const float* X    = (const float*)d_in[0];
  const float* SI   = (const float*)d_in[1];
  const float* keys = (const float*)d_in[2];
  const float* vals = (const float*)d_in[3];
  const float* ES   = (const float*)d_in[4];
  const float* bias = (const float*)d_in[5];
  float* out = (float*)d_out;
  float* out_sel = out + SLAB;

  char* ws = (char*)d_ws;
  int*   counts   = (int*)(ws + 0);
  int*   cursor   = (int*)(ws + 512);
  int*   offsets  = (int*)(ws + 1024);
  int4*  jm       = (int4*)(ws + 2048);
  int*   list_tok = (int*)(ws + 57344);
  float* list_w   = (float*)(ws + 450560);
  float* w6       = (float*)(ws + 919552);
  int*   sel_e    = (int*)(ws + 1312768);
  u16*   Xb       = (u16*)(ws + 1576960);        // 32MB
  u16*   Kf       = (u16*)(ws + 35131392);       // 8MB
  u16*   Vf       = (u16*)(ws + 43520000);       // 8MB
  u16*   part     = (u16*)(ws + 51908608);       // 6 x 32MB slabs

  hipMemsetAsync(counts, 0, 1024, stream);

  prep_router_kernel<<<NB_FUSED, 256, 0, stream>>>(X, Xb, keys, Kf, vals, Vf,
                                                   SI, ES, bias, out_sel, w6,
                                                   sel_e, counts);
  scan_kernel<<<1, 256, 0, stream>>>(counts, offsets, jm);
  scatter_kernel<<<NTOK / 256, 256, 0, stream>>>(sel_e, w6, offsets, cursor, list_tok, list_w);
  ffn_kernel<<<NJOBS_F, 256, 0, stream>>>(Xb, Kf, Vf, jm, list_tok, list_w, part);
  reduce_kernel<<<SLAB / (256 * 8), 256, 0, stream>>>(part, out);
}